// Round 3
// baseline (688.978 us; speedup 1.0000x reference)
//
#include <hip/hip_runtime.h>
#include <hip/hip_bf16.h>
#include <math.h>

#define T_TOK 8192
#define EMB   1024
#define HID   1536
#define NE    8
#define RB_TOK 128                 // tokens per router block
#define R_BLOCKS (T_TOK / RB_TOK)  // 64

typedef float  floatx4 __attribute__((ext_vector_type(4)));
typedef __bf16 bf16x8  __attribute__((ext_vector_type(8)));
typedef __bf16 bf16x4  __attribute__((ext_vector_type(4)));

// ---- workspace layout (bytes) ----
#define WS_COUNTS   0           // 8*4
#define WS_OFFSETS  1024        // 9*4
#define WS_FLAGS    2048        // 7*4 (1 = tensor is fp32, 0 = bf16)
#define WS_TOKMAP   4096        // T*NE*4 = 262144   (token,slot) -> (expert<<16|pos)
#define WS_TOKLIST  266240      // NE*T*4 = 262144
#define WS_YBUF     528384      // 16384*1024*2 = 33554432
#define WS_W1T      34082816    // 8*1536*1024*2 = 25165824
#define WS_W2T      59248640    // 25165824
#define WS_H        84414464    // 16640*1536*2 = 51118080
#define WS_NEEDED   135532544

// ---- dual-dtype scalar load ----
__device__ __forceinline__ float eload(const void* p, size_t idx, bool f32) {
  return f32 ? ((const float*)p)[idx] : (float)(((const __bf16*)p)[idx]);
}

// ---- dual-dtype 8-element load (result as bf16x8) ----
template <bool F32>
__device__ __forceinline__ bf16x8 ld8t(const void* p, size_t idx) {
  if (F32) {
    const float* g = (const float*)p + idx;
    float4 u = *(const float4*)g;
    float4 v = *(const float4*)(g + 4);
    bf16x8 r;
    r[0] = (__bf16)u.x; r[1] = (__bf16)u.y; r[2] = (__bf16)u.z; r[3] = (__bf16)u.w;
    r[4] = (__bf16)v.x; r[5] = (__bf16)v.y; r[6] = (__bf16)v.z; r[7] = (__bf16)v.w;
    return r;
  }
  return *(const bf16x8*)((const __bf16*)p + idx);
}

// ---------------- dtype sniff: one block per input tensor ----------------
__global__ __launch_bounds__(256)
void sniff_kernel(const void* p0, const void* p1, const void* p2, const void* p3,
                  const void* p4, const void* p5, const void* p6, int* flags) {
  const void* ps[7] = {p0, p1, p2, p3, p4, p5, p6};
  const int nelem[7] = {T_TOK * EMB, EMB * NE, NE, NE * EMB * HID, NE * HID, NE * HID * EMB, NE * EMB};
  int t = blockIdx.x;
  const unsigned* w = (const unsigned*)ps[t];
  int nw = nelem[t] / 2;
  if (nw > 2048) nw = 2048;
  __shared__ int s_pl, s_nz;
  if (threadIdx.x == 0) { s_pl = 0; s_nz = 0; }
  __syncthreads();
  int pl = 0, nz = 0;
  for (int i = threadIdx.x; i < nw; i += 256) {
    unsigned v = w[i];
    if (v == 0) continue;
    nz++;
    unsigned e = (v >> 23) & 0xFF;
    if (e >= 100 && e <= 150) pl++;
  }
  atomicAdd(&s_pl, pl);
  atomicAdd(&s_nz, nz);
  __syncthreads();
  if (threadIdx.x == 0) flags[t] = (2 * s_pl > s_nz) ? 1 : 0;
}

// ---------------- router: 64 blocks, block-aggregated binning ----------------
// Per block: 128 tokens (32 per wave). LDS per-expert lists; ONE global
// atomicAdd per (block,expert) to reserve space (512 same-line atomics total
// vs 16384 in round 2 -> removes the ~200us serialization).
__global__ __launch_bounds__(256)
void router_kernel(const void* __restrict__ x, const void* __restrict__ Wr,
                   const void* __restrict__ br, const int* __restrict__ kptr,
                   const int* __restrict__ flags,
                   int* __restrict__ counts, int* __restrict__ tok_list,
                   int* __restrict__ tokmap) {
  const bool xf32  = flags[0] != 0;
  const bool wrf32 = flags[1] != 0;
  const bool brf32 = flags[2] != 0;
  __shared__ int lists[NE][RB_TOK];
  __shared__ int lcount[NE];
  const int wave = threadIdx.x >> 6;
  const int lane = threadIdx.x & 63;
  if (threadIdx.x < NE) lcount[threadIdx.x] = 0;
  __syncthreads();

  int k = kptr[0];
  if (k < 1) k = 1; if (k > NE) k = NE;

  const int t0 = blockIdx.x * RB_TOK + wave * (RB_TOK / 4);
  for (int tt = 0; tt < RB_TOK / 4; ++tt) {
    const int t = t0 + tt;
    float acc[NE];
#pragma unroll
    for (int e = 0; e < NE; ++e) acc[e] = 0.f;
    if (wrf32) {
      for (int i = lane; i < EMB; i += 64) {
        float xv = eload(x, (size_t)t * EMB + i, xf32);
        const float* wr = (const float*)Wr + (size_t)i * NE;
#pragma unroll
        for (int e = 0; e < NE; ++e) acc[e] += xv * wr[e];
      }
    } else {
      for (int i = lane; i < EMB; i += 64) {
        float xv = eload(x, (size_t)t * EMB + i, xf32);
        bf16x8 wv = *(const bf16x8*)((const __bf16*)Wr + (size_t)i * NE);
#pragma unroll
        for (int e = 0; e < NE; ++e) acc[e] += xv * (float)wv[e];
      }
    }
#pragma unroll
    for (int e = 0; e < NE; ++e) {
#pragma unroll
      for (int off = 32; off > 0; off >>= 1)
        acc[e] += __shfl_xor(acc[e], off, 64);
    }
    if (lane == 0) {
      float lg[NE];
#pragma unroll
      for (int e = 0; e < NE; ++e) lg[e] = acc[e] + eload(br, e, brf32);
      for (int s = 0; s < k; ++s) {
        int bi = 0; float bv = lg[0];
#pragma unroll
        for (int e = 1; e < NE; ++e) { if (lg[e] > bv) { bv = lg[e]; bi = e; } }
        lg[bi] = -3.0e38f;
        int pos = atomicAdd(&lcount[bi], 1);     // LDS atomic: fast
        lists[bi][pos] = t * 8 + s;
      }
    }
  }
  __syncthreads();

  // copy-out: expert e handled by wave e&3
  for (int e = wave; e < NE; e += 4) {
    const int len = lcount[e];
    int base = 0;
    if (lane == 0 && len > 0) base = atomicAdd(&counts[e], len);
    base = __shfl(base, 0, 64);
    for (int i = lane; i < len; i += 64) {
      int v = lists[e][i];
      int t = v >> 3, s = v & 7;
      tok_list[e * T_TOK + base + i] = t;
      tokmap[t * NE + s] = (e << 16) | (base + i);
    }
  }
}

__global__ void offsets_kernel(const int* __restrict__ counts, int* __restrict__ offsets) {
  if (threadIdx.x == 0 && blockIdx.x == 0) {
    int s = 0;
    for (int e = 0; e < NE; ++e) { offsets[e] = s; s += counts[e]; }
    offsets[NE] = s;
  }
}

// ---------------- per-expert transpose: in [K][N] -> out [N][K] (bf16) ----------------
__global__ __launch_bounds__(256)
void transpose_kernel(const void* __restrict__ in, __bf16* __restrict__ out, int K, int N,
                      const int* __restrict__ flags, int fidx) {
  const bool f32 = flags[fidx] != 0;
  __shared__ __bf16 tile[64][65];
  size_t eoff = (size_t)blockIdx.z * (size_t)K * (size_t)N;
  int n0 = blockIdx.x * 64;
  int k0 = blockIdx.y * 64;
  int tx = threadIdx.x & 63;
  int ty = threadIdx.x >> 6;
#pragma unroll
  for (int i = 0; i < 16; ++i) {
    int r = i * 4 + ty;
    tile[r][tx] = (__bf16)eload(in, eoff + (size_t)(k0 + r) * N + (n0 + tx), f32);
  }
  __syncthreads();
#pragma unroll
  for (int i = 0; i < 16; ++i) {
    int r = i * 4 + ty;
    out[eoff + (size_t)(n0 + r) * K + (k0 + tx)] = tile[tx][r];
  }
}

// ---------------- GEMM1 K-loop (templated on A dtype) ----------------
template <bool XF32>
__device__ __forceinline__ void gemm1_kloop(
    const void* __restrict__ x, size_t offA0, size_t offA1,
    const __bf16* __restrict__ gB0, const __bf16* __restrict__ gB1,
    __bf16* As, __bf16* Bs, int r0, int r1, int kc,
    int wm, int wn, int mr, int kq, floatx4 (&acc)[4][4]) {
  for (int kb = 0; kb < EMB / 32; ++kb) {
    bf16x8 a0 = ld8t<XF32>(x, offA0);
    bf16x8 a1 = ld8t<XF32>(x, offA1);
    bf16x8 b0 = *(const bf16x8*)gB0;
    bf16x8 b1v = *(const bf16x8*)gB1;
    offA0 += 32; offA1 += 32; gB0 += 32; gB1 += 32;
    __syncthreads();
    *(bf16x8*)(As + r0 * 32 + kc) = a0;
    *(bf16x8*)(As + r1 * 32 + kc) = a1;
    *(bf16x8*)(Bs + r0 * 32 + kc) = b0;
    *(bf16x8*)(Bs + r1 * 32 + kc) = b1v;
    __syncthreads();
    bf16x8 af[4], bfr[4];
#pragma unroll
    for (int i = 0; i < 4; ++i) af[i]  = *(const bf16x8*)(As + (wm + i * 16 + mr) * 32 + kq);
#pragma unroll
    for (int j = 0; j < 4; ++j) bfr[j] = *(const bf16x8*)(Bs + (wn + j * 16 + mr) * 32 + kq);
#pragma unroll
    for (int i = 0; i < 4; ++i)
#pragma unroll
      for (int j = 0; j < 4; ++j)
        acc[i][j] = __builtin_amdgcn_mfma_f32_16x16x32_bf16(af[i], bfr[j], acc[i][j], 0, 0, 0);
  }
}

// ---------------- GEMM1: h = gelu(x_gather @ W1[e] + b1[e]) ----------------
__global__ __launch_bounds__(256, 2)
void gemm1_kernel(const void* __restrict__ x, const __bf16* __restrict__ w1t,
                  const void* __restrict__ b1, const int* __restrict__ counts,
                  const int* __restrict__ offsets, const int* __restrict__ tok_list,
                  const int* __restrict__ flags, __bf16* __restrict__ hbuf) {
  const int e  = blockIdx.z;
  const int mT = blockIdx.y;
  const int nT = blockIdx.x;
  const int cnt = counts[e];
  if (mT * 128 >= cnt) return;
  const bool xf32  = flags[0] != 0;
  const bool b1f32 = flags[4] != 0;

  __shared__ __align__(16) __bf16 As[128 * 32];
  __shared__ __align__(16) __bf16 Bs[128 * 32];

  const int wave = threadIdx.x >> 6;
  const int lane = threadIdx.x & 63;
  const int sr = lane >> 2;
  const int kc = (lane & 3) * 8;
  const int r0 = wave * 16 + sr;
  const int r1 = 64 + wave * 16 + sr;

  const int tokA0 = tok_list[e * T_TOK + mT * 128 + r0];  // pad entries are 0 (memset)
  const int tokA1 = tok_list[e * T_TOK + mT * 128 + r1];
  size_t offA0 = (size_t)tokA0 * EMB + kc;
  size_t offA1 = (size_t)tokA1 * EMB + kc;
  const __bf16* gB0 = w1t + ((size_t)e * HID + nT * 128 + r0) * EMB + kc;
  const __bf16* gB1 = w1t + ((size_t)e * HID + nT * 128 + r1) * EMB + kc;

  const int wm = (wave & 1) * 64;
  const int wn = (wave >> 1) * 64;
  const int mr = lane & 15;
  const int kq = (lane >> 4) * 8;

  floatx4 acc[4][4];
#pragma unroll
  for (int i = 0; i < 4; ++i)
#pragma unroll
    for (int j = 0; j < 4; ++j) acc[i][j] = (floatx4){0.f, 0.f, 0.f, 0.f};

  if (xf32) gemm1_kloop<true >(x, offA0, offA1, gB0, gB1, As, Bs, r0, r1, kc, wm, wn, mr, kq, acc);
  else      gemm1_kloop<false>(x, offA0, offA1, gB0, gB1, As, Bs, r0, r1, kc, wm, wn, mr, kq, acc);

  // epilogue: C/D layout col=lane&15, row=(lane>>4)*4+reg
  const int hBase   = offsets[e] + mT * 128;
  const int colBase = nT * 128 + wn + mr;
  float b1v4[4];
#pragma unroll
  for (int j = 0; j < 4; ++j) b1v4[j] = eload(b1, (size_t)e * HID + colBase + j * 16, b1f32);
#pragma unroll
  for (int i = 0; i < 4; ++i) {
    const int rowLoc = wm + i * 16 + (lane >> 4) * 4;
#pragma unroll
    for (int r = 0; r < 4; ++r) {
      const int row = rowLoc + r;
      if (mT * 128 + row < cnt) {
        __bf16* hp = hbuf + (size_t)(hBase + row) * HID + colBase;
#pragma unroll
        for (int j = 0; j < 4; ++j) {
          float v = acc[i][j][r] + b1v4[j];
          float g = 0.5f * v * (1.0f + erff(v * 0.70710678118654752f));
          hp[j * 16] = (__bf16)g;
        }
      }
    }
  }
}

// ---------------- GEMM2: ybuf[row] = h @ W2[e] + b2[e]  (no atomics) ----------------
__global__ __launch_bounds__(256, 2)
void gemm2_kernel(const __bf16* __restrict__ hbuf, const __bf16* __restrict__ w2t,
                  const void* __restrict__ b2, const int* __restrict__ counts,
                  const int* __restrict__ offsets, const int* __restrict__ flags,
                  __bf16* __restrict__ ybuf) {
  const int e  = blockIdx.z;
  const int mT = blockIdx.y;
  const int nT = blockIdx.x;
  const int cnt = counts[e];
  if (mT * 128 >= cnt) return;
  const bool b2f32 = flags[6] != 0;

  __shared__ __align__(16) __bf16 As[128 * 32];
  __shared__ __align__(16) __bf16 Bs[128 * 32];

  const int wave = threadIdx.x >> 6;
  const int lane = threadIdx.x & 63;
  const int sr = lane >> 2;
  const int kc = (lane & 3) * 8;
  const int r0 = wave * 16 + sr;
  const int r1 = 64 + wave * 16 + sr;

  const int rowBase = offsets[e] + mT * 128;     // compact row space (hbuf & ybuf)
  const __bf16* gA0 = hbuf + (size_t)(rowBase + r0) * HID + kc;
  const __bf16* gA1 = hbuf + (size_t)(rowBase + r1) * HID + kc;
  const __bf16* gB0 = w2t + ((size_t)e * EMB + nT * 128 + r0) * HID + kc;
  const __bf16* gB1 = w2t + ((size_t)e * EMB + nT * 128 + r1) * HID + kc;

  const int wm = (wave & 1) * 64;
  const int wn = (wave >> 1) * 64;
  const int mr = lane & 15;
  const int kq = (lane >> 4) * 8;

  floatx4 acc[4][4];
#pragma unroll
  for (int i = 0; i < 4; ++i)
#pragma unroll
    for (int j = 0; j < 4; ++j) acc[i][j] = (floatx4){0.f, 0.f, 0.f, 0.f};

  for (int kb = 0; kb < HID / 32; ++kb) {
    bf16x8 a0 = *(const bf16x8*)gA0;
    bf16x8 a1 = *(const bf16x8*)gA1;
    bf16x8 b0 = *(const bf16x8*)gB0;
    bf16x8 b1v = *(const bf16x8*)gB1;
    gA0 += 32; gA1 += 32; gB0 += 32; gB1 += 32;
    __syncthreads();
    *(bf16x8*)(As + r0 * 32 + kc) = a0;
    *(bf16x8*)(As + r1 * 32 + kc) = a1;
    *(bf16x8*)(Bs + r0 * 32 + kc) = b0;
    *(bf16x8*)(Bs + r1 * 32 + kc) = b1v;
    __syncthreads();
    bf16x8 af[4], bfr[4];
#pragma unroll
    for (int i = 0; i < 4; ++i) af[i]  = *(const bf16x8*)(As + (wm + i * 16 + mr) * 32 + kq);
#pragma unroll
    for (int j = 0; j < 4; ++j) bfr[j] = *(const bf16x8*)(Bs + (wn + j * 16 + mr) * 32 + kq);
#pragma unroll
    for (int i = 0; i < 4; ++i)
#pragma unroll
      for (int j = 0; j < 4; ++j)
        acc[i][j] = __builtin_amdgcn_mfma_f32_16x16x32_bf16(af[i], bfr[j], acc[i][j], 0, 0, 0);
  }

  const int colBase = nT * 128 + wn + mr;
  float b2v4[4];
#pragma unroll
  for (int j = 0; j < 4; ++j) b2v4[j] = eload(b2, (size_t)e * EMB + colBase + j * 16, b2f32);
#pragma unroll
  for (int i = 0; i < 4; ++i) {
    const int rowLoc = wm + i * 16 + (lane >> 4) * 4;
#pragma unroll
    for (int r = 0; r < 4; ++r) {
      const int row = rowLoc + r;
      if (mT * 128 + row < cnt) {
        __bf16* yp = ybuf + (size_t)(rowBase + row) * EMB + colBase;
#pragma unroll
        for (int j = 0; j < 4; ++j)
          yp[j * 16] = (__bf16)(acc[i][j][r] + b2v4[j]);
      }
    }
  }
}

// ---------------- combine: out[t] = (sum_s ybuf[row(t,s)]) / k ----------------
__global__ __launch_bounds__(256)
void combine_kernel(const __bf16* __restrict__ ybuf, const int* __restrict__ tokmap,
                    const int* __restrict__ offsets, const int* __restrict__ kptr,
                    const int* __restrict__ flags, void* __restrict__ out) {
  const bool f32 = flags[0] != 0;
  const int wave = threadIdx.x >> 6;
  const int lane = threadIdx.x & 63;
  const int t = blockIdx.x * 4 + wave;
  int k = kptr[0];
  if (k < 1) k = 1; if (k > NE) k = NE;
  const float invk = 1.0f / (float)k;
  int rows[NE];
  for (int s = 0; s < k; ++s) {
    int v = tokmap[t * NE + s];
    rows[s] = offsets[v >> 16] + (v & 0xFFFF);
  }
#pragma unroll
  for (int c = 0; c < 2; ++c) {
    const int i = c * 512 + lane * 8;
    float a[8];
#pragma unroll
    for (int j = 0; j < 8; ++j) a[j] = 0.f;
    for (int s = 0; s < k; ++s) {
      bf16x8 y = *(const bf16x8*)(ybuf + (size_t)rows[s] * EMB + i);
#pragma unroll
      for (int j = 0; j < 8; ++j) a[j] += (float)y[j];
    }
    if (f32) {
      float* op = (float*)out + (size_t)t * EMB + i;
      float4 u = {a[0] * invk, a[1] * invk, a[2] * invk, a[3] * invk};
      float4 v = {a[4] * invk, a[5] * invk, a[6] * invk, a[7] * invk};
      *(float4*)op = u;
      *(float4*)(op + 4) = v;
    } else {
      bf16x8 o;
#pragma unroll
      for (int j = 0; j < 8; ++j) o[j] = (__bf16)(a[j] * invk);
      *(bf16x8*)((__bf16*)out + (size_t)t * EMB + i) = o;
    }
  }
}

extern "C" void kernel_launch(void* const* d_in, const int* in_sizes, int n_in,
                              void* d_out, int out_size, void* d_ws, size_t ws_size,
                              hipStream_t stream) {
  (void)in_sizes; (void)n_in; (void)out_size;
  if (ws_size < (size_t)WS_NEEDED) return;

  const void* x  = d_in[0];
  const void* Wr = d_in[1];
  const void* br = d_in[2];
  const void* W1 = d_in[3];
  const void* b1 = d_in[4];
  const void* W2 = d_in[5];
  const void* b2 = d_in[6];
  const int* kptr = (const int*)d_in[7];

  char* ws = (char*)d_ws;
  int*    counts   = (int*)(ws + WS_COUNTS);
  int*    offsets  = (int*)(ws + WS_OFFSETS);
  int*    flags    = (int*)(ws + WS_FLAGS);
  int*    tokmap   = (int*)(ws + WS_TOKMAP);
  int*    tok_list = (int*)(ws + WS_TOKLIST);
  __bf16* ybuf     = (__bf16*)(ws + WS_YBUF);
  __bf16* w1t      = (__bf16*)(ws + WS_W1T);
  __bf16* w2t      = (__bf16*)(ws + WS_W2T);
  __bf16* hbuf     = (__bf16*)(ws + WS_H);

  // zero control region: counts/offsets/flags/tokmap/tok_list (0.5 MB)
  hipMemsetAsync(ws, 0, WS_YBUF, stream);

  sniff_kernel<<<dim3(7), 256, 0, stream>>>(x, Wr, br, W1, b1, W2, b2, flags);

  transpose_kernel<<<dim3(HID / 64, EMB / 64, NE), 256, 0, stream>>>(W1, w1t, EMB, HID, flags, 3);
  transpose_kernel<<<dim3(EMB / 64, HID / 64, NE), 256, 0, stream>>>(W2, w2t, HID, EMB, flags, 5);

  router_kernel<<<dim3(R_BLOCKS), 256, 0, stream>>>(x, Wr, br, kptr, flags, counts, tok_list, tokmap);
  offsets_kernel<<<1, 64, 0, stream>>>(counts, offsets);

  gemm1_kernel<<<dim3(HID / 128, T_TOK / 128, NE), 256, 0, stream>>>(
      x, w1t, b1, counts, offsets, tok_list, flags, hbuf);
  gemm2_kernel<<<dim3(EMB / 128, T_TOK / 128, NE), 256, 0, stream>>>(
      hbuf, w2t, b2, counts, offsets, flags, ybuf);

  combine_kernel<<<dim3(T_TOK / 4), 256, 0, stream>>>(ybuf, tokmap, offsets, kptr, flags, d_out);
}

// Round 4
// 475.035 us; speedup vs baseline: 1.4504x; 1.4504x over previous
//
#include <hip/hip_runtime.h>
#include <hip/hip_bf16.h>
#include <math.h>

#define T_TOK 8192
#define EMB   1024
#define HID   1536
#define NE    8
#define NBINB 64                  // binning blocks
#define BINTOK (T_TOK / NBINB)    // 128 tokens per binning block

typedef float  floatx4 __attribute__((ext_vector_type(4)));
typedef __bf16 bf16x8  __attribute__((ext_vector_type(8)));

// ---- workspace layout (bytes) ----
#define WS_COUNTS   0           // 8*4
#define WS_OFFSETS  1024        // 9*4
#define WS_FLAGS    2048        // 7*4 (1 = tensor is fp32, 0 = bf16)
#define WS_BHIST    4096        // 64*8*4 = 2048 (block histograms -> block bases)
#define WS_TOKMAP   8192        // T*8*4 = 262144; logits' topk then (expert<<16|pos)
#define WS_TOKLIST  270336      // NE*T*4 = 262144
#define WS_YBUF     532480      // 16384*1024*2 = 33554432
#define WS_W1T      34086912    // 8*1536*1024*2 = 25165824
#define WS_W2T      59252736    // 25165824
#define WS_H        84418560    // 16512*1536*2 = 50724864 (16384 + 127 pad + round)
#define WS_NEEDED   135143424   // < 135532544 proven available in r2/r3

// ---- dual-dtype scalar load ----
__device__ __forceinline__ float eload(const void* p, size_t idx, bool f32) {
  return f32 ? ((const float*)p)[idx] : (float)(((const __bf16*)p)[idx]);
}

// ---- dual-dtype 8-element load (result as bf16x8) ----
template <bool F32>
__device__ __forceinline__ bf16x8 ld8t(const void* p, size_t idx) {
  if (F32) {
    const float* g = (const float*)p + idx;
    float4 u = *(const float4*)g;
    float4 v = *(const float4*)(g + 4);
    bf16x8 r;
    r[0] = (__bf16)u.x; r[1] = (__bf16)u.y; r[2] = (__bf16)u.z; r[3] = (__bf16)u.w;
    r[4] = (__bf16)v.x; r[5] = (__bf16)v.y; r[6] = (__bf16)v.z; r[7] = (__bf16)v.w;
    return r;
  }
  return *(const bf16x8*)((const __bf16*)p + idx);
}

// ---------------- dtype sniff ----------------
__global__ __launch_bounds__(256)
void sniff_kernel(const void* p0, const void* p1, const void* p2, const void* p3,
                  const void* p4, const void* p5, const void* p6, int* flags) {
  const void* ps[7] = {p0, p1, p2, p3, p4, p5, p6};
  const int nelem[7] = {T_TOK * EMB, EMB * NE, NE, NE * EMB * HID, NE * HID, NE * HID * EMB, NE * EMB};
  int t = blockIdx.x;
  const unsigned* w = (const unsigned*)ps[t];
  int nw = nelem[t] / 2;
  if (nw > 2048) nw = 2048;
  __shared__ int s_pl, s_nz;
  if (threadIdx.x == 0) { s_pl = 0; s_nz = 0; }
  __syncthreads();
  int pl = 0, nz = 0;
  for (int i = threadIdx.x; i < nw; i += 256) {
    unsigned v = w[i];
    if (v == 0) continue;
    nz++;
    unsigned e = (v >> 23) & 0xFF;
    if (e >= 100 && e <= 150) pl++;
  }
  atomicAdd(&s_pl, pl);
  atomicAdd(&s_nz, nz);
  __syncthreads();
  if (threadIdx.x == 0) flags[t] = (2 * s_pl > s_nz) ? 1 : 0;
}

// ---------------- logits + top-k: one wave per token, fully parallel ----------------
__global__ __launch_bounds__(256)
void logits_kernel(const void* __restrict__ x, const void* __restrict__ Wr,
                   const void* __restrict__ br, const int* __restrict__ kptr,
                   const int* __restrict__ flags, int* __restrict__ topk) {
  const bool xf32  = flags[0] != 0;
  const bool wrf32 = flags[1] != 0;
  const bool brf32 = flags[2] != 0;
  const int wave = threadIdx.x >> 6;
  const int lane = threadIdx.x & 63;
  const int t = blockIdx.x * 4 + wave;

  // lane covers x elements [lane*16, lane*16+16) -- 32 contiguous bytes (bf16)
  float xv[16];
  {
    size_t base = (size_t)t * EMB + lane * 16;
    if (xf32) {
      const float* g = (const float*)x + base;
#pragma unroll
      for (int j = 0; j < 16; ++j) xv[j] = g[j];
    } else {
      bf16x8 u = *(const bf16x8*)((const __bf16*)x + base);
      bf16x8 v = *(const bf16x8*)((const __bf16*)x + base + 8);
#pragma unroll
      for (int j = 0; j < 8; ++j) { xv[j] = (float)u[j]; xv[8 + j] = (float)v[j]; }
    }
  }
  float acc[NE];
#pragma unroll
  for (int e = 0; e < NE; ++e) acc[e] = 0.f;
  if (wrf32) {
#pragma unroll
    for (int j = 0; j < 16; ++j) {
      const float* wr = (const float*)Wr + (size_t)(lane * 16 + j) * NE;
#pragma unroll
      for (int e = 0; e < NE; ++e) acc[e] += xv[j] * wr[e];
    }
  } else {
#pragma unroll
    for (int j = 0; j < 16; ++j) {
      bf16x8 wr = *(const bf16x8*)((const __bf16*)Wr + (size_t)(lane * 16 + j) * NE);
#pragma unroll
      for (int e = 0; e < NE; ++e) acc[e] += xv[j] * (float)wr[e];
    }
  }
#pragma unroll
  for (int e = 0; e < NE; ++e) {
#pragma unroll
    for (int off = 32; off > 0; off >>= 1)
      acc[e] += __shfl_xor(acc[e], off, 64);
  }
  if (lane == 0) {
    int k = kptr[0];
    if (k < 1) k = 1; if (k > NE) k = NE;
    float lg[NE];
#pragma unroll
    for (int e = 0; e < NE; ++e) lg[e] = acc[e] + eload(br, e, brf32);
    for (int s = 0; s < k; ++s) {
      int bi = 0; float bv = lg[0];
#pragma unroll
      for (int e = 1; e < NE; ++e) { if (lg[e] > bv) { bv = lg[e]; bi = e; } }
      lg[bi] = -3.0e38f;
      topk[t * 8 + s] = bi;
    }
  }
}

// ---------------- binning pass 1: per-block expert histograms (no global atomics) ----------------
__global__ __launch_bounds__(128)
void bin1_kernel(const int* __restrict__ topk, const int* __restrict__ kptr,
                 int* __restrict__ bhist) {
  __shared__ int lhist[NE];
  if (threadIdx.x < NE) lhist[threadIdx.x] = 0;
  __syncthreads();
  int k = kptr[0];
  if (k < 1) k = 1; if (k > NE) k = NE;
  const int t = blockIdx.x * BINTOK + threadIdx.x;
  for (int s = 0; s < k; ++s) {
    int e = topk[t * 8 + s] & 7;
    atomicAdd(&lhist[e], 1);
  }
  __syncthreads();
  if (threadIdx.x < NE) bhist[blockIdx.x * NE + threadIdx.x] = lhist[threadIdx.x];
}

// ---------------- scan: bhist -> per-block bases; counts; offsets ----------------
__global__ __launch_bounds__(256)
void scan_kernel(int* __restrict__ bhist, int* __restrict__ counts, int* __restrict__ offsets) {
  __shared__ int sh[NBINB * NE];
  __shared__ int scnt[NE];
  __shared__ int soff[NE + 1];
  const int tid = threadIdx.x;
  for (int i = tid; i < NBINB * NE; i += 256) sh[i] = bhist[i];
  __syncthreads();
  if (tid < NE) {
    int s = 0;
    for (int b = 0; b < NBINB; ++b) s += sh[b * NE + tid];
    scnt[tid] = s;
  }
  __syncthreads();
  if (tid == 0) {
    int s = 0;
    for (int e = 0; e < NE; ++e) { soff[e] = s; s += scnt[e]; }
    soff[NE] = s;
  }
  __syncthreads();
  if (tid < NE) {
    int run = soff[tid];
    for (int b = 0; b < NBINB; ++b) {
      int v = sh[b * NE + tid];
      sh[b * NE + tid] = run;
      run += v;
    }
  }
  __syncthreads();
  for (int i = tid; i < NBINB * NE; i += 256) bhist[i] = sh[i];
  if (tid < NE) counts[tid] = scnt[tid];
  if (tid < NE + 1) offsets[tid] = soff[tid];
}

// ---------------- binning pass 2: deterministic placement ----------------
__global__ __launch_bounds__(128)
void bin2_kernel(const int* __restrict__ bhist, const int* __restrict__ kptr,
                 int* __restrict__ tok_list, int* __restrict__ tokmap) {
  __shared__ int lbase[NE];
  __shared__ int lcnt[NE];
  if (threadIdx.x < NE) {
    lbase[threadIdx.x] = bhist[blockIdx.x * NE + threadIdx.x];
    lcnt[threadIdx.x] = 0;
  }
  __syncthreads();
  int k = kptr[0];
  if (k < 1) k = 1; if (k > NE) k = NE;
  const int t = blockIdx.x * BINTOK + threadIdx.x;
  for (int s = 0; s < k; ++s) {
    int e = tokmap[t * 8 + s] & 7;               // topk value (same buffer, pre-overwrite)
    int pos = atomicAdd(&lcnt[e], 1);            // LDS atomic
    int row = lbase[e] + pos;                    // global row in expert-e compact space
    tok_list[e * T_TOK + (row - 0)] = t;         // row is already expert-global (includes offsets)
    tokmap[t * 8 + s] = (e << 16) | row;
  }
}

// NOTE: bhist bases already include offsets[e] (scan starts run at soff[e]),
// so `row` above is the COMPACT GLOBAL row; tok_list is indexed per-expert
// from its own slot [e*T_TOK + (row - offsets[e])]. Fixed below in kernel body.

// ---------------- per-expert transpose: in [K][N] -> out [N][K] (bf16) ----------------
__global__ __launch_bounds__(256)
void transpose_kernel(const void* __restrict__ in, __bf16* __restrict__ out, int K, int N,
                      const int* __restrict__ flags, int fidx) {
  const bool f32 = flags[fidx] != 0;
  __shared__ __bf16 tile[64][65];
  size_t eoff = (size_t)blockIdx.z * (size_t)K * (size_t)N;
  int n0 = blockIdx.x * 64;
  int k0 = blockIdx.y * 64;
  int tx = threadIdx.x & 63;
  int ty = threadIdx.x >> 6;
#pragma unroll
  for (int i = 0; i < 16; ++i) {
    int r = i * 4 + ty;
    tile[r][tx] = (__bf16)eload(in, eoff + (size_t)(k0 + r) * N + (n0 + tx), f32);
  }
  __syncthreads();
#pragma unroll
  for (int i = 0; i < 16; ++i) {
    int r = i * 4 + ty;
    out[eoff + (size_t)(n0 + r) * K + (k0 + tx)] = tile[tx][r];
  }
}

// ---------------- pipelined GEMM K-loop (register prefetch of next tile) ----------------
template <bool XF32>
__device__ __forceinline__ void gemm_kloop(
    const void* __restrict__ aptr, size_t offA0, size_t offA1,
    const __bf16* __restrict__ gB0, const __bf16* __restrict__ gB1,
    __bf16* As, __bf16* Bs, int r0, int r1, int kc,
    int wm, int wn, int mr, int kq, int niter, floatx4 (&acc)[4][4]) {
  bf16x8 s0 = ld8t<XF32>(aptr, offA0);
  bf16x8 s1 = ld8t<XF32>(aptr, offA1);
  bf16x8 s2 = *(const bf16x8*)gB0;
  bf16x8 s3 = *(const bf16x8*)gB1;
  for (int kb = 0; kb < niter; ++kb) {
    bf16x8 n0 = s0, n1 = s1, n2 = s2, n3 = s3;
    if (kb + 1 < niter) {                          // wave-uniform branch
      offA0 += 32; offA1 += 32; gB0 += 32; gB1 += 32;
      n0 = ld8t<XF32>(aptr, offA0);
      n1 = ld8t<XF32>(aptr, offA1);
      n2 = *(const bf16x8*)gB0;
      n3 = *(const bf16x8*)gB1;
    }
    __syncthreads();                               // previous iteration's LDS readers done
    *(bf16x8*)(As + r0 * 32 + kc) = s0;
    *(bf16x8*)(As + r1 * 32 + kc) = s1;
    *(bf16x8*)(Bs + r0 * 32 + kc) = s2;
    *(bf16x8*)(Bs + r1 * 32 + kc) = s3;
    __syncthreads();                               // staging visible
    bf16x8 af[4], bfr[4];
#pragma unroll
    for (int i = 0; i < 4; ++i) af[i]  = *(const bf16x8*)(As + (wm + i * 16 + mr) * 32 + kq);
#pragma unroll
    for (int j = 0; j < 4; ++j) bfr[j] = *(const bf16x8*)(Bs + (wn + j * 16 + mr) * 32 + kq);
#pragma unroll
    for (int i = 0; i < 4; ++i)
#pragma unroll
      for (int j = 0; j < 4; ++j)
        acc[i][j] = __builtin_amdgcn_mfma_f32_16x16x32_bf16(af[i], bfr[j], acc[i][j], 0, 0, 0);
    s0 = n0; s1 = n1; s2 = n2; s3 = n3;
  }
}

// ---------------- GEMM1: h = gelu(x_gather @ W1[e] + b1[e]) ----------------
__global__ __launch_bounds__(256, 2)
void gemm1_kernel(const void* __restrict__ x, const __bf16* __restrict__ w1t,
                  const void* __restrict__ b1, const int* __restrict__ counts,
                  const int* __restrict__ offsets, const int* __restrict__ tok_list,
                  const int* __restrict__ flags, __bf16* __restrict__ hbuf) {
  const int e  = blockIdx.z;
  const int mT = blockIdx.y;
  const int nT = blockIdx.x;
  const int cnt = counts[e];
  if (mT * 128 >= cnt) return;
  const bool xf32  = flags[0] != 0;
  const bool b1f32 = flags[4] != 0;

  __shared__ __align__(16) __bf16 As[128 * 32];
  __shared__ __align__(16) __bf16 Bs[128 * 32];

  const int wave = threadIdx.x >> 6;
  const int lane = threadIdx.x & 63;
  const int sr = lane >> 2;
  const int kc = (lane & 3) * 8;
  const int r0 = wave * 16 + sr;
  const int r1 = 64 + wave * 16 + sr;

  const int tokA0 = tok_list[e * T_TOK + mT * 128 + r0];  // pad entries are 0 (memset)
  const int tokA1 = tok_list[e * T_TOK + mT * 128 + r1];
  size_t offA0 = (size_t)tokA0 * EMB + kc;
  size_t offA1 = (size_t)tokA1 * EMB + kc;
  const __bf16* gB0 = w1t + ((size_t)e * HID + nT * 128 + r0) * EMB + kc;
  const __bf16* gB1 = w1t + ((size_t)e * HID + nT * 128 + r1) * EMB + kc;

  const int wm = (wave & 1) * 64;
  const int wn = (wave >> 1) * 64;
  const int mr = lane & 15;
  const int kq = (lane >> 4) * 8;

  floatx4 acc[4][4];
#pragma unroll
  for (int i = 0; i < 4; ++i)
#pragma unroll
    for (int j = 0; j < 4; ++j) acc[i][j] = (floatx4){0.f, 0.f, 0.f, 0.f};

  if (xf32) gemm_kloop<true >(x, offA0, offA1, gB0, gB1, As, Bs, r0, r1, kc, wm, wn, mr, kq, EMB / 32, acc);
  else      gemm_kloop<false>(x, offA0, offA1, gB0, gB1, As, Bs, r0, r1, kc, wm, wn, mr, kq, EMB / 32, acc);

  const int hBase   = offsets[e] + mT * 128;
  const int colBase = nT * 128 + wn + mr;
  float b1v4[4];
#pragma unroll
  for (int j = 0; j < 4; ++j) b1v4[j] = eload(b1, (size_t)e * HID + colBase + j * 16, b1f32);
#pragma unroll
  for (int i = 0; i < 4; ++i) {
    const int rowLoc = wm + i * 16 + (lane >> 4) * 4;
#pragma unroll
    for (int r = 0; r < 4; ++r) {
      const int row = rowLoc + r;
      if (mT * 128 + row < cnt) {
        __bf16* hp = hbuf + (size_t)(hBase + row) * HID + colBase;
#pragma unroll
        for (int j = 0; j < 4; ++j) {
          float v = acc[i][j][r] + b1v4[j];
          float g = 0.5f * v * (1.0f + erff(v * 0.70710678118654752f));
          hp[j * 16] = (__bf16)g;
        }
      }
    }
  }
}

// ---------------- GEMM2: ybuf[row] = h @ W2[e] + b2[e] ----------------
__global__ __launch_bounds__(256, 2)
void gemm2_kernel(const __bf16* __restrict__ hbuf, const __bf16* __restrict__ w2t,
                  const void* __restrict__ b2, const int* __restrict__ counts,
                  const int* __restrict__ offsets, const int* __restrict__ flags,
                  __bf16* __restrict__ ybuf) {
  const int e  = blockIdx.z;
  const int mT = blockIdx.y;
  const int nT = blockIdx.x;
  const int cnt = counts[e];
  if (mT * 128 >= cnt) return;
  const bool b2f32 = flags[6] != 0;

  __shared__ __align__(16) __bf16 As[128 * 32];
  __shared__ __align__(16) __bf16 Bs[128 * 32];

  const int wave = threadIdx.x >> 6;
  const int lane = threadIdx.x & 63;
  const int sr = lane >> 2;
  const int kc = (lane & 3) * 8;
  const int r0 = wave * 16 + sr;
  const int r1 = 64 + wave * 16 + sr;

  const int rowBase = offsets[e] + mT * 128;
  size_t offA0 = (size_t)(rowBase + r0) * HID + kc;
  size_t offA1 = (size_t)(rowBase + r1) * HID + kc;
  const __bf16* gB0 = w2t + ((size_t)e * EMB + nT * 128 + r0) * HID + kc;
  const __bf16* gB1 = w2t + ((size_t)e * EMB + nT * 128 + r1) * HID + kc;

  const int wm = (wave & 1) * 64;
  const int wn = (wave >> 1) * 64;
  const int mr = lane & 15;
  const int kq = (lane >> 4) * 8;

  floatx4 acc[4][4];
#pragma unroll
  for (int i = 0; i < 4; ++i)
#pragma unroll
    for (int j = 0; j < 4; ++j) acc[i][j] = (floatx4){0.f, 0.f, 0.f, 0.f};

  gemm_kloop<false>(hbuf, offA0, offA1, gB0, gB1, As, Bs, r0, r1, kc, wm, wn, mr, kq, HID / 32, acc);

  const int colBase = nT * 128 + wn + mr;
  float b2v4[4];
#pragma unroll
  for (int j = 0; j < 4; ++j) b2v4[j] = eload(b2, (size_t)e * EMB + colBase + j * 16, b2f32);
#pragma unroll
  for (int i = 0; i < 4; ++i) {
    const int rowLoc = wm + i * 16 + (lane >> 4) * 4;
#pragma unroll
    for (int r = 0; r < 4; ++r) {
      const int row = rowLoc + r;
      if (mT * 128 + row < cnt) {
        __bf16* yp = ybuf + (size_t)(rowBase + row) * EMB + colBase;
#pragma unroll
        for (int j = 0; j < 4; ++j)
          yp[j * 16] = (__bf16)(acc[i][j][r] + b2v4[j]);
      }
    }
  }
}

// ---------------- combine: out[t] = (sum_s ybuf[row(t,s)]) / k ----------------
__global__ __launch_bounds__(256)
void combine_kernel(const __bf16* __restrict__ ybuf, const int* __restrict__ tokmap,
                    const int* __restrict__ kptr, const int* __restrict__ flags,
                    void* __restrict__ out) {
  const bool f32 = flags[0] != 0;
  const int wave = threadIdx.x >> 6;
  const int lane = threadIdx.x & 63;
  const int t = blockIdx.x * 4 + wave;
  int k = kptr[0];
  if (k < 1) k = 1; if (k > NE) k = NE;
  const float invk = 1.0f / (float)k;
  int rows[NE];
  for (int s = 0; s < k; ++s) rows[s] = tokmap[t * 8 + s] & 0xFFFF;   // compact global row
#pragma unroll
  for (int c = 0; c < 2; ++c) {
    const int i = c * 512 + lane * 8;
    float a[8];
#pragma unroll
    for (int j = 0; j < 8; ++j) a[j] = 0.f;
    for (int s = 0; s < k; ++s) {
      bf16x8 y = *(const bf16x8*)(ybuf + (size_t)rows[s] * EMB + i);
#pragma unroll
      for (int j = 0; j < 8; ++j) a[j] += (float)y[j];
    }
    if (f32) {
      float* op = (float*)out + (size_t)t * EMB + i;
      float4 u = {a[0] * invk, a[1] * invk, a[2] * invk, a[3] * invk};
      float4 v = {a[4] * invk, a[5] * invk, a[6] * invk, a[7] * invk};
      *(float4*)op = u;
      *(float4*)(op + 4) = v;
    } else {
      bf16x8 o;
#pragma unroll
      for (int j = 0; j < 8; ++j) o[j] = (__bf16)(a[j] * invk);
      *(bf16x8*)((__bf16*)out + (size_t)t * EMB + i) = o;
    }
  }
}

// ---- corrected bin2 (tok_list wants expert-LOCAL index; bases include offsets) ----
__global__ __launch_bounds__(128)
void bin2_fix_kernel(const int* __restrict__ bhist, const int* __restrict__ offsets,
                     const int* __restrict__ kptr,
                     int* __restrict__ tok_list, int* __restrict__ tokmap) {
  __shared__ int lbase[NE];
  __shared__ int lcnt[NE];
  if (threadIdx.x < NE) {
    lbase[threadIdx.x] = bhist[blockIdx.x * NE + threadIdx.x];
    lcnt[threadIdx.x] = 0;
  }
  __syncthreads();
  int k = kptr[0];
  if (k < 1) k = 1; if (k > NE) k = NE;
  const int t = blockIdx.x * BINTOK + threadIdx.x;
  for (int s = 0; s < k; ++s) {
    int e = tokmap[t * 8 + s] & 7;               // topk value written by logits_kernel
    int pos = atomicAdd(&lcnt[e], 1);
    int grow = lbase[e] + pos;                   // compact global row (includes offsets[e])
    tok_list[e * T_TOK + (grow - offsets[e])] = t;
    tokmap[t * 8 + s] = (e << 16) | grow;
  }
}

extern "C" void kernel_launch(void* const* d_in, const int* in_sizes, int n_in,
                              void* d_out, int out_size, void* d_ws, size_t ws_size,
                              hipStream_t stream) {
  (void)in_sizes; (void)n_in; (void)out_size;
  if (ws_size < (size_t)WS_NEEDED) return;

  const void* x  = d_in[0];
  const void* Wr = d_in[1];
  const void* br = d_in[2];
  const void* W1 = d_in[3];
  const void* b1 = d_in[4];
  const void* W2 = d_in[5];
  const void* b2 = d_in[6];
  const int* kptr = (const int*)d_in[7];

  char* ws = (char*)d_ws;
  int*    counts   = (int*)(ws + WS_COUNTS);
  int*    offsets  = (int*)(ws + WS_OFFSETS);
  int*    flags    = (int*)(ws + WS_FLAGS);
  int*    bhist    = (int*)(ws + WS_BHIST);
  int*    tokmap   = (int*)(ws + WS_TOKMAP);
  int*    tok_list = (int*)(ws + WS_TOKLIST);
  __bf16* ybuf     = (__bf16*)(ws + WS_YBUF);
  __bf16* w1t      = (__bf16*)(ws + WS_W1T);
  __bf16* w2t      = (__bf16*)(ws + WS_W2T);
  __bf16* hbuf     = (__bf16*)(ws + WS_H);

  // zero control region (tokmap/tok_list zeros double as safe pad tokens)
  hipMemsetAsync(ws, 0, WS_YBUF, stream);

  sniff_kernel<<<dim3(7), 256, 0, stream>>>(x, Wr, br, W1, b1, W2, b2, flags);

  transpose_kernel<<<dim3(HID / 64, EMB / 64, NE), 256, 0, stream>>>(W1, w1t, EMB, HID, flags, 3);
  transpose_kernel<<<dim3(EMB / 64, HID / 64, NE), 256, 0, stream>>>(W2, w2t, HID, EMB, flags, 5);

  logits_kernel<<<dim3(T_TOK / 4), 256, 0, stream>>>(x, Wr, br, kptr, flags, tokmap);
  bin1_kernel<<<dim3(NBINB), 128, 0, stream>>>(tokmap, kptr, bhist);
  scan_kernel<<<dim3(1), 256, 0, stream>>>(bhist, counts, offsets);
  bin2_fix_kernel<<<dim3(NBINB), 128, 0, stream>>>(bhist, offsets, kptr, tok_list, tokmap);

  gemm1_kernel<<<dim3(HID / 128, T_TOK / 128, NE), 256, 0, stream>>>(
      x, w1t, b1, counts, offsets, tok_list, flags, hbuf);
  gemm2_kernel<<<dim3(EMB / 128, T_TOK / 128, NE), 256, 0, stream>>>(
      hbuf, w2t, b2, counts, offsets, flags, ybuf);

  combine_kernel<<<dim3(T_TOK / 4), 256, 0, stream>>>(ybuf, tokmap, kptr, flags, d_out);
}

// Round 5
// 460.996 us; speedup vs baseline: 1.4945x; 1.0305x over previous
//
#include <hip/hip_runtime.h>
#include <hip/hip_bf16.h>
#include <math.h>

#define T_TOK 8192
#define EMB   1024
#define HID   1536
#define NE    8
#define NBINB 64
#define BINTOK (T_TOK / NBINB)
#define LDS_STRIDE 72            // 64 k-elems + 8 pad (144 B rows, 16B-aligned)

typedef float  floatx4 __attribute__((ext_vector_type(4)));
typedef __bf16 bf16x8  __attribute__((ext_vector_type(8)));

// ---- workspace layout (bytes) ----
#define WS_COUNTS   0
#define WS_OFFSETS  1024
#define WS_FLAGS    2048
#define WS_BHIST    4096
#define WS_TOKMAP   8192        // T*8*4
#define WS_TOKLIST  270336      // NE*T*4
#define WS_YBUF     532480      // 16384*1024*2
#define WS_W1T      34086912    // 25165824
#define WS_W2T      59252736    // 25165824
#define WS_H        84418560    // 16512*1536*2
#define WS_NEEDED   135143424

__device__ __forceinline__ float eload(const void* p, size_t idx, bool f32) {
  return f32 ? ((const float*)p)[idx] : (float)(((const __bf16*)p)[idx]);
}

template <bool F32>
__device__ __forceinline__ bf16x8 ld8t(const void* p, size_t idx) {
  if (F32) {
    const float* g = (const float*)p + idx;
    float4 u = *(const float4*)g;
    float4 v = *(const float4*)(g + 4);
    bf16x8 r;
    r[0] = (__bf16)u.x; r[1] = (__bf16)u.y; r[2] = (__bf16)u.z; r[3] = (__bf16)u.w;
    r[4] = (__bf16)v.x; r[5] = (__bf16)v.y; r[6] = (__bf16)v.z; r[7] = (__bf16)v.w;
    return r;
  }
  return *(const bf16x8*)((const __bf16*)p + idx);
}

// ---------------- dtype sniff ----------------
__global__ __launch_bounds__(256)
void sniff_kernel(const void* p0, const void* p1, const void* p2, const void* p3,
                  const void* p4, const void* p5, const void* p6, int* flags) {
  const void* ps[7] = {p0, p1, p2, p3, p4, p5, p6};
  const int nelem[7] = {T_TOK * EMB, EMB * NE, NE, NE * EMB * HID, NE * HID, NE * HID * EMB, NE * EMB};
  int t = blockIdx.x;
  const unsigned* w = (const unsigned*)ps[t];
  int nw = nelem[t] / 2;
  if (nw > 2048) nw = 2048;
  __shared__ int s_pl, s_nz;
  if (threadIdx.x == 0) { s_pl = 0; s_nz = 0; }
  __syncthreads();
  int pl = 0, nz = 0;
  for (int i = threadIdx.x; i < nw; i += 256) {
    unsigned v = w[i];
    if (v == 0) continue;
    nz++;
    unsigned e = (v >> 23) & 0xFF;
    if (e >= 100 && e <= 150) pl++;
  }
  atomicAdd(&s_pl, pl);
  atomicAdd(&s_nz, nz);
  __syncthreads();
  if (threadIdx.x == 0) flags[t] = (2 * s_pl > s_nz) ? 1 : 0;
}

// ---------------- logits + top-k: one wave per token ----------------
__global__ __launch_bounds__(256)
void logits_kernel(const void* __restrict__ x, const void* __restrict__ Wr,
                   const void* __restrict__ br, const int* __restrict__ kptr,
                   const int* __restrict__ flags, int* __restrict__ topk) {
  const bool xf32  = flags[0] != 0;
  const bool wrf32 = flags[1] != 0;
  const bool brf32 = flags[2] != 0;
  const int wave = threadIdx.x >> 6;
  const int lane = threadIdx.x & 63;
  const int t = blockIdx.x * 4 + wave;

  float xv[16];
  {
    size_t base = (size_t)t * EMB + lane * 16;
    if (xf32) {
      const float* g = (const float*)x + base;
#pragma unroll
      for (int j = 0; j < 16; ++j) xv[j] = g[j];
    } else {
      bf16x8 u = *(const bf16x8*)((const __bf16*)x + base);
      bf16x8 v = *(const bf16x8*)((const __bf16*)x + base + 8);
#pragma unroll
      for (int j = 0; j < 8; ++j) { xv[j] = (float)u[j]; xv[8 + j] = (float)v[j]; }
    }
  }
  float acc[NE];
#pragma unroll
  for (int e = 0; e < NE; ++e) acc[e] = 0.f;
  if (wrf32) {
#pragma unroll
    for (int j = 0; j < 16; ++j) {
      const float* wr = (const float*)Wr + (size_t)(lane * 16 + j) * NE;
#pragma unroll
      for (int e = 0; e < NE; ++e) acc[e] += xv[j] * wr[e];
    }
  } else {
#pragma unroll
    for (int j = 0; j < 16; ++j) {
      bf16x8 wr = *(const bf16x8*)((const __bf16*)Wr + (size_t)(lane * 16 + j) * NE);
#pragma unroll
      for (int e = 0; e < NE; ++e) acc[e] += xv[j] * (float)wr[e];
    }
  }
#pragma unroll
  for (int e = 0; e < NE; ++e) {
#pragma unroll
    for (int off = 32; off > 0; off >>= 1)
      acc[e] += __shfl_xor(acc[e], off, 64);
  }
  if (lane == 0) {
    int k = kptr[0];
    if (k < 1) k = 1; if (k > NE) k = NE;
    float lg[NE];
#pragma unroll
    for (int e = 0; e < NE; ++e) lg[e] = acc[e] + eload(br, e, brf32);
    for (int s = 0; s < k; ++s) {
      int bi = 0; float bv = lg[0];
#pragma unroll
      for (int e = 1; e < NE; ++e) { if (lg[e] > bv) { bv = lg[e]; bi = e; } }
      lg[bi] = -3.0e38f;
      topk[t * 8 + s] = bi;
    }
  }
}

// ---------------- binning: histogram -> scan -> place (no global atomics) ----------------
__global__ __launch_bounds__(128)
void bin1_kernel(const int* __restrict__ topk, const int* __restrict__ kptr,
                 int* __restrict__ bhist) {
  __shared__ int lhist[NE];
  if (threadIdx.x < NE) lhist[threadIdx.x] = 0;
  __syncthreads();
  int k = kptr[0];
  if (k < 1) k = 1; if (k > NE) k = NE;
  const int t = blockIdx.x * BINTOK + threadIdx.x;
  for (int s = 0; s < k; ++s) atomicAdd(&lhist[topk[t * 8 + s] & 7], 1);
  __syncthreads();
  if (threadIdx.x < NE) bhist[blockIdx.x * NE + threadIdx.x] = lhist[threadIdx.x];
}

__global__ __launch_bounds__(256)
void scan_kernel(int* __restrict__ bhist, int* __restrict__ counts, int* __restrict__ offsets) {
  __shared__ int sh[NBINB * NE];
  __shared__ int scnt[NE];
  __shared__ int soff[NE + 1];
  const int tid = threadIdx.x;
  for (int i = tid; i < NBINB * NE; i += 256) sh[i] = bhist[i];
  __syncthreads();
  if (tid < NE) {
    int s = 0;
    for (int b = 0; b < NBINB; ++b) s += sh[b * NE + tid];
    scnt[tid] = s;
  }
  __syncthreads();
  if (tid == 0) {
    int s = 0;
    for (int e = 0; e < NE; ++e) { soff[e] = s; s += scnt[e]; }
    soff[NE] = s;
  }
  __syncthreads();
  if (tid < NE) {
    int run = soff[tid];
    for (int b = 0; b < NBINB; ++b) {
      int v = sh[b * NE + tid];
      sh[b * NE + tid] = run;
      run += v;
    }
  }
  __syncthreads();
  for (int i = tid; i < NBINB * NE; i += 256) bhist[i] = sh[i];
  if (tid < NE) counts[tid] = scnt[tid];
  if (tid < NE + 1) offsets[tid] = soff[tid];
}

__global__ __launch_bounds__(128)
void bin2_kernel(const int* __restrict__ bhist, const int* __restrict__ offsets,
                 const int* __restrict__ kptr,
                 int* __restrict__ tok_list, int* __restrict__ tokmap) {
  __shared__ int lbase[NE];
  __shared__ int lcnt[NE];
  if (threadIdx.x < NE) {
    lbase[threadIdx.x] = bhist[blockIdx.x * NE + threadIdx.x];
    lcnt[threadIdx.x] = 0;
  }
  __syncthreads();
  int k = kptr[0];
  if (k < 1) k = 1; if (k > NE) k = NE;
  const int t = blockIdx.x * BINTOK + threadIdx.x;
  for (int s = 0; s < k; ++s) {
    int e = tokmap[t * 8 + s] & 7;
    int pos = atomicAdd(&lcnt[e], 1);
    int grow = lbase[e] + pos;                   // compact global row (includes offsets[e])
    tok_list[e * T_TOK + (grow - offsets[e])] = t;
    tokmap[t * 8 + s] = (e << 16) | grow;
  }
}

// ---------------- per-expert transpose: [K][N] -> [N][K] bf16 ----------------
__global__ __launch_bounds__(256)
void transpose_kernel(const void* __restrict__ in, __bf16* __restrict__ out, int K, int N,
                      const int* __restrict__ flags, int fidx) {
  const bool f32 = flags[fidx] != 0;
  __shared__ __bf16 tile[64][65];
  size_t eoff = (size_t)blockIdx.z * (size_t)K * (size_t)N;
  int n0 = blockIdx.x * 64;
  int k0 = blockIdx.y * 64;
  int tx = threadIdx.x & 63;
  int ty = threadIdx.x >> 6;
#pragma unroll
  for (int i = 0; i < 16; ++i) {
    int r = i * 4 + ty;
    tile[r][tx] = (__bf16)eload(in, eoff + (size_t)(k0 + r) * N + (n0 + tx), f32);
  }
  __syncthreads();
#pragma unroll
  for (int i = 0; i < 16; ++i) {
    int r = i * 4 + ty;
    out[eoff + (size_t)(n0 + r) * K + (k0 + tx)] = tile[tx][r];
  }
}

// ---------------- BK=64 pipelined K-loop ----------------
// Staging: thread tid covers rows r[t]=(tid>>3)+32t (t=0..3), k-chunk (tid&7)*8.
// Fragments: two k-halves s=0,1 -> 32 MFMA per barrier pair.
template <bool XF32>
__device__ __forceinline__ void kloop64(
    const void* __restrict__ aBase, size_t a0, size_t a1, size_t a2, size_t a3,
    const __bf16* __restrict__ bBase, size_t b0, size_t b1, size_t b2, size_t b3,
    __bf16* As, __bf16* Bs, int tid, int niter, int wm, int wn, int mr, int kq8,
    floatx4 (&acc)[4][4]) {
  const int kc8 = (tid & 7) * 8;
  const int rr  = (tid >> 3);
  bf16x8 ca0 = ld8t<XF32>(aBase, a0), ca1 = ld8t<XF32>(aBase, a1);
  bf16x8 ca2 = ld8t<XF32>(aBase, a2), ca3 = ld8t<XF32>(aBase, a3);
  bf16x8 cb0 = *(const bf16x8*)(bBase + b0), cb1 = *(const bf16x8*)(bBase + b1);
  bf16x8 cb2 = *(const bf16x8*)(bBase + b2), cb3 = *(const bf16x8*)(bBase + b3);
  for (int kb = 0; kb < niter; ++kb) {
    bf16x8 na0 = ca0, na1 = ca1, na2 = ca2, na3 = ca3;
    bf16x8 nb0 = cb0, nb1 = cb1, nb2 = cb2, nb3 = cb3;
    if (kb + 1 < niter) {
      size_t d = (size_t)(kb + 1) * 64;
      na0 = ld8t<XF32>(aBase, a0 + d); na1 = ld8t<XF32>(aBase, a1 + d);
      na2 = ld8t<XF32>(aBase, a2 + d); na3 = ld8t<XF32>(aBase, a3 + d);
      nb0 = *(const bf16x8*)(bBase + b0 + d); nb1 = *(const bf16x8*)(bBase + b1 + d);
      nb2 = *(const bf16x8*)(bBase + b2 + d); nb3 = *(const bf16x8*)(bBase + b3 + d);
    }
    __syncthreads();
    *(bf16x8*)(As + (rr +  0) * LDS_STRIDE + kc8) = ca0;
    *(bf16x8*)(As + (rr + 32) * LDS_STRIDE + kc8) = ca1;
    *(bf16x8*)(As + (rr + 64) * LDS_STRIDE + kc8) = ca2;
    *(bf16x8*)(As + (rr + 96) * LDS_STRIDE + kc8) = ca3;
    *(bf16x8*)(Bs + (rr +  0) * LDS_STRIDE + kc8) = cb0;
    *(bf16x8*)(Bs + (rr + 32) * LDS_STRIDE + kc8) = cb1;
    *(bf16x8*)(Bs + (rr + 64) * LDS_STRIDE + kc8) = cb2;
    *(bf16x8*)(Bs + (rr + 96) * LDS_STRIDE + kc8) = cb3;
    __syncthreads();
#pragma unroll
    for (int s = 0; s < 2; ++s) {
      bf16x8 af[4], bfr[4];
#pragma unroll
      for (int i = 0; i < 4; ++i)
        af[i]  = *(const bf16x8*)(As + (wm + i * 16 + mr) * LDS_STRIDE + s * 32 + kq8);
#pragma unroll
      for (int j = 0; j < 4; ++j)
        bfr[j] = *(const bf16x8*)(Bs + (wn + j * 16 + mr) * LDS_STRIDE + s * 32 + kq8);
#pragma unroll
      for (int i = 0; i < 4; ++i)
#pragma unroll
        for (int j = 0; j < 4; ++j)
          acc[i][j] = __builtin_amdgcn_mfma_f32_16x16x32_bf16(af[i], bfr[j], acc[i][j], 0, 0, 0);
    }
    ca0 = na0; ca1 = na1; ca2 = na2; ca3 = na3;
    cb0 = nb0; cb1 = nb1; cb2 = nb2; cb3 = nb3;
  }
}

// ---------------- GEMM1: h = gelu(x_gather @ W1[e] + b1[e]) ----------------
// 1D grid, e = blockIdx.x & 7 -> expert-per-XCD L2 locality.
__global__ __launch_bounds__(256, 2)
void gemm1_kernel(const void* __restrict__ x, const __bf16* __restrict__ w1t,
                  const void* __restrict__ b1, const int* __restrict__ counts,
                  const int* __restrict__ offsets, const int* __restrict__ tok_list,
                  const int* __restrict__ flags, __bf16* __restrict__ hbuf) {
  const int flat = blockIdx.x;
  const int e  = flat & 7;
  const int rest = flat >> 3;
  const int mT = rest & 63;
  const int nT = rest >> 6;
  const int cnt = counts[e];
  if (mT * 128 >= cnt) return;
  const bool xf32  = flags[0] != 0;
  const bool b1f32 = flags[4] != 0;

  __shared__ __align__(16) __bf16 As[128 * LDS_STRIDE];
  __shared__ __align__(16) __bf16 Bs[128 * LDS_STRIDE];

  const int tid  = threadIdx.x;
  const int wave = tid >> 6;
  const int lane = tid & 63;
  const int kc8 = (tid & 7) * 8;
  const int rr  = tid >> 3;

  int tk0 = tok_list[e * T_TOK + mT * 128 + rr +  0];
  int tk1 = tok_list[e * T_TOK + mT * 128 + rr + 32];
  int tk2 = tok_list[e * T_TOK + mT * 128 + rr + 64];
  int tk3 = tok_list[e * T_TOK + mT * 128 + rr + 96];
  size_t a0 = (size_t)tk0 * EMB + kc8, a1 = (size_t)tk1 * EMB + kc8;
  size_t a2 = (size_t)tk2 * EMB + kc8, a3 = (size_t)tk3 * EMB + kc8;
  size_t bb = ((size_t)e * HID + nT * 128) * EMB + kc8;
  size_t b0 = bb + (size_t)(rr +  0) * EMB, b1o = bb + (size_t)(rr + 32) * EMB;
  size_t b2 = bb + (size_t)(rr + 64) * EMB, b3 = bb + (size_t)(rr + 96) * EMB;

  const int wm = (wave & 1) * 64;
  const int wn = (wave >> 1) * 64;
  const int mr = lane & 15;
  const int kq8 = (lane >> 4) * 8;

  floatx4 acc[4][4];
#pragma unroll
  for (int i = 0; i < 4; ++i)
#pragma unroll
    for (int j = 0; j < 4; ++j) acc[i][j] = (floatx4){0.f, 0.f, 0.f, 0.f};

  if (xf32) kloop64<true >(x, a0, a1, a2, a3, w1t, b0, b1o, b2, b3, As, Bs, tid, EMB / 64, wm, wn, mr, kq8, acc);
  else      kloop64<false>(x, a0, a1, a2, a3, w1t, b0, b1o, b2, b3, As, Bs, tid, EMB / 64, wm, wn, mr, kq8, acc);

  const int hBase   = offsets[e] + mT * 128;
  const int colBase = nT * 128 + wn + mr;
  float b1v4[4];
#pragma unroll
  for (int j = 0; j < 4; ++j) b1v4[j] = eload(b1, (size_t)e * HID + colBase + j * 16, b1f32);
#pragma unroll
  for (int i = 0; i < 4; ++i) {
    const int rowLoc = wm + i * 16 + (lane >> 4) * 4;
#pragma unroll
    for (int r = 0; r < 4; ++r) {
      const int row = rowLoc + r;
      if (mT * 128 + row < cnt) {
        __bf16* hp = hbuf + (size_t)(hBase + row) * HID + colBase;
#pragma unroll
        for (int j = 0; j < 4; ++j) {
          float v = acc[i][j][r] + b1v4[j];
          float g = 0.5f * v * (1.0f + erff(v * 0.70710678118654752f));
          hp[j * 16] = (__bf16)g;
        }
      }
    }
  }
}

// ---------------- GEMM2: ybuf[row] = h @ W2[e] + b2[e] ----------------
__global__ __launch_bounds__(256, 2)
void gemm2_kernel(const __bf16* __restrict__ hbuf, const __bf16* __restrict__ w2t,
                  const void* __restrict__ b2, const int* __restrict__ counts,
                  const int* __restrict__ offsets, const int* __restrict__ flags,
                  __bf16* __restrict__ ybuf) {
  const int flat = blockIdx.x;
  const int e  = flat & 7;
  const int rest = flat >> 3;
  const int mT = rest & 63;
  const int nT = rest >> 6;
  const int cnt = counts[e];
  if (mT * 128 >= cnt) return;
  const bool b2f32 = flags[6] != 0;

  __shared__ __align__(16) __bf16 As[128 * LDS_STRIDE];
  __shared__ __align__(16) __bf16 Bs[128 * LDS_STRIDE];

  const int tid  = threadIdx.x;
  const int wave = tid >> 6;
  const int lane = tid & 63;
  const int kc8 = (tid & 7) * 8;
  const int rr  = tid >> 3;

  const int rowBase = offsets[e] + mT * 128;
  size_t ab = (size_t)rowBase * HID + kc8;
  size_t a0 = ab + (size_t)(rr +  0) * HID, a1 = ab + (size_t)(rr + 32) * HID;
  size_t a2 = ab + (size_t)(rr + 64) * HID, a3 = ab + (size_t)(rr + 96) * HID;
  size_t bb = ((size_t)e * EMB + nT * 128) * HID + kc8;
  size_t b0 = bb + (size_t)(rr +  0) * HID, b1o = bb + (size_t)(rr + 32) * HID;
  size_t b2o = bb + (size_t)(rr + 64) * HID, b3 = bb + (size_t)(rr + 96) * HID;

  const int wm = (wave & 1) * 64;
  const int wn = (wave >> 1) * 64;
  const int mr = lane & 15;
  const int kq8 = (lane >> 4) * 8;

  floatx4 acc[4][4];
#pragma unroll
  for (int i = 0; i < 4; ++i)
#pragma unroll
    for (int j = 0; j < 4; ++j) acc[i][j] = (floatx4){0.f, 0.f, 0.f, 0.f};

  kloop64<false>(hbuf, a0, a1, a2, a3, w2t, b0, b1o, b2o, b3, As, Bs, tid, HID / 64, wm, wn, mr, kq8, acc);

  const int colBase = nT * 128 + wn + mr;
  float b2v4[4];
#pragma unroll
  for (int j = 0; j < 4; ++j) b2v4[j] = eload(b2, (size_t)e * EMB + colBase + j * 16, b2f32);
#pragma unroll
  for (int i = 0; i < 4; ++i) {
    const int rowLoc = wm + i * 16 + (lane >> 4) * 4;
#pragma unroll
    for (int r = 0; r < 4; ++r) {
      const int row = rowLoc + r;
      if (mT * 128 + row < cnt) {
        __bf16* yp = ybuf + (size_t)(rowBase + row) * EMB + colBase;
#pragma unroll
        for (int j = 0; j < 4; ++j)
          yp[j * 16] = (__bf16)(acc[i][j][r] + b2v4[j]);
      }
    }
  }
}

// ---------------- combine: out[t] = (sum_s ybuf[row(t,s)]) / k ----------------
__global__ __launch_bounds__(256)
void combine_kernel(const __bf16* __restrict__ ybuf, const int* __restrict__ tokmap,
                    const int* __restrict__ kptr, const int* __restrict__ flags,
                    void* __restrict__ out) {
  const bool f32 = flags[0] != 0;
  const int wave = threadIdx.x >> 6;
  const int lane = threadIdx.x & 63;
  const int t = blockIdx.x * 4 + wave;
  int k = kptr[0];
  if (k < 1) k = 1; if (k > NE) k = NE;
  const float invk = 1.0f / (float)k;
  int rows[NE];
  for (int s = 0; s < k; ++s) rows[s] = tokmap[t * 8 + s] & 0xFFFF;
#pragma unroll
  for (int c = 0; c < 2; ++c) {
    const int i = c * 512 + lane * 8;
    float a[8];
#pragma unroll
    for (int j = 0; j < 8; ++j) a[j] = 0.f;
    for (int s = 0; s < k; ++s) {
      bf16x8 y = *(const bf16x8*)(ybuf + (size_t)rows[s] * EMB + i);
#pragma unroll
      for (int j = 0; j < 8; ++j) a[j] += (float)y[j];
    }
    if (f32) {
      float* op = (float*)out + (size_t)t * EMB + i;
      float4 u = {a[0] * invk, a[1] * invk, a[2] * invk, a[3] * invk};
      float4 v = {a[4] * invk, a[5] * invk, a[6] * invk, a[7] * invk};
      *(float4*)op = u;
      *(float4*)(op + 4) = v;
    } else {
      bf16x8 o;
#pragma unroll
      for (int j = 0; j < 8; ++j) o[j] = (__bf16)(a[j] * invk);
      *(bf16x8*)((__bf16*)out + (size_t)t * EMB + i) = o;
    }
  }
}

extern "C" void kernel_launch(void* const* d_in, const int* in_sizes, int n_in,
                              void* d_out, int out_size, void* d_ws, size_t ws_size,
                              hipStream_t stream) {
  (void)in_sizes; (void)n_in; (void)out_size;
  if (ws_size < (size_t)WS_NEEDED) return;

  const void* x  = d_in[0];
  const void* Wr = d_in[1];
  const void* br = d_in[2];
  const void* W1 = d_in[3];
  const void* b1 = d_in[4];
  const void* W2 = d_in[5];
  const void* b2 = d_in[6];
  const int* kptr = (const int*)d_in[7];

  char* ws = (char*)d_ws;
  int*    counts   = (int*)(ws + WS_COUNTS);
  int*    offsets  = (int*)(ws + WS_OFFSETS);
  int*    flags    = (int*)(ws + WS_FLAGS);
  int*    bhist    = (int*)(ws + WS_BHIST);
  int*    tokmap   = (int*)(ws + WS_TOKMAP);
  int*    tok_list = (int*)(ws + WS_TOKLIST);
  __bf16* ybuf     = (__bf16*)(ws + WS_YBUF);
  __bf16* w1t      = (__bf16*)(ws + WS_W1T);
  __bf16* w2t      = (__bf16*)(ws + WS_W2T);
  __bf16* hbuf     = (__bf16*)(ws + WS_H);

  hipMemsetAsync(ws, 0, WS_YBUF, stream);

  sniff_kernel<<<dim3(7), 256, 0, stream>>>(x, Wr, br, W1, b1, W2, b2, flags);

  transpose_kernel<<<dim3(HID / 64, EMB / 64, NE), 256, 0, stream>>>(W1, w1t, EMB, HID, flags, 3);
  transpose_kernel<<<dim3(EMB / 64, HID / 64, NE), 256, 0, stream>>>(W2, w2t, HID, EMB, flags, 5);

  logits_kernel<<<dim3(T_TOK / 4), 256, 0, stream>>>(x, Wr, br, kptr, flags, tokmap);
  bin1_kernel<<<dim3(NBINB), 128, 0, stream>>>(tokmap, kptr, bhist);
  scan_kernel<<<dim3(1), 256, 0, stream>>>(bhist, counts, offsets);
  bin2_kernel<<<dim3(NBINB), 128, 0, stream>>>(bhist, offsets, kptr, tok_list, tokmap);

  gemm1_kernel<<<dim3(8 * 64 * (HID / 128)), 256, 0, stream>>>(
      x, w1t, b1, counts, offsets, tok_list, flags, hbuf);
  gemm2_kernel<<<dim3(8 * 64 * (EMB / 128)), 256, 0, stream>>>(
      hbuf, w2t, b2, counts, offsets, flags, ybuf);

  combine_kernel<<<dim3(T_TOK / 4), 256, 0, stream>>>(ybuf, tokmap, kptr, flags, d_out);
}

// Round 6
// 433.984 us; speedup vs baseline: 1.5876x; 1.0622x over previous
//
#include <hip/hip_runtime.h>
#include <hip/hip_bf16.h>
#include <math.h>

#define T_TOK 8192
#define EMB   1024
#define HID   1536
#define NE    8
#define NBINB 64
#define BINTOK (T_TOK / NBINB)

typedef float  floatx4 __attribute__((ext_vector_type(4)));
typedef __bf16 bf16x8  __attribute__((ext_vector_type(8)));

// ---- workspace layout (bytes) ----
#define WS_COUNTS   0
#define WS_OFFSETS  1024
#define WS_FLAGS    2048
#define WS_BHIST    4096
#define WS_TOKMAP   8192        // T*8*4
#define WS_TOKLIST  270336      // NE*T*4
#define WS_YBUF     532480      // 16384*1024*2
#define WS_W1T      34086912    // 25165824
#define WS_W2T      59252736    // 25165824
#define WS_H        84418560    // 16512*1536*2
#define WS_NEEDED   135143424

__device__ __forceinline__ float eload(const void* p, size_t idx, bool f32) {
  return f32 ? ((const float*)p)[idx] : (float)(((const __bf16*)p)[idx]);
}

__device__ __forceinline__ bf16x8 ld8f32(const void* p, size_t idx) {
  const float* g = (const float*)p + idx;
  float4 u = *(const float4*)g;
  float4 v = *(const float4*)(g + 4);
  bf16x8 r;
  r[0] = (__bf16)u.x; r[1] = (__bf16)u.y; r[2] = (__bf16)u.z; r[3] = (__bf16)u.w;
  r[4] = (__bf16)v.x; r[5] = (__bf16)v.y; r[6] = (__bf16)v.z; r[7] = (__bf16)v.w;
  return r;
}

// async global->LDS, 16B per lane; LDS dest = wave-uniform base + lane*16
__device__ __forceinline__ void glds16(const void* g, void* l) {
  __builtin_amdgcn_global_load_lds(
      (const __attribute__((address_space(1))) unsigned int*)g,
      (__attribute__((address_space(3))) unsigned int*)l, 16, 0, 0);
}

// ---------------- dtype sniff ----------------
__global__ __launch_bounds__(256)
void sniff_kernel(const void* p0, const void* p1, const void* p2, const void* p3,
                  const void* p4, const void* p5, const void* p6, int* flags) {
  const void* ps[7] = {p0, p1, p2, p3, p4, p5, p6};
  const int nelem[7] = {T_TOK * EMB, EMB * NE, NE, NE * EMB * HID, NE * HID, NE * HID * EMB, NE * EMB};
  int t = blockIdx.x;
  const unsigned* w = (const unsigned*)ps[t];
  int nw = nelem[t] / 2;
  if (nw > 2048) nw = 2048;
  __shared__ int s_pl, s_nz;
  if (threadIdx.x == 0) { s_pl = 0; s_nz = 0; }
  __syncthreads();
  int pl = 0, nz = 0;
  for (int i = threadIdx.x; i < nw; i += 256) {
    unsigned v = w[i];
    if (v == 0) continue;
    nz++;
    unsigned e = (v >> 23) & 0xFF;
    if (e >= 100 && e <= 150) pl++;
  }
  atomicAdd(&s_pl, pl);
  atomicAdd(&s_nz, nz);
  __syncthreads();
  if (threadIdx.x == 0) flags[t] = (2 * s_pl > s_nz) ? 1 : 0;
}

// ---------------- logits + top-k: one wave per token ----------------
__global__ __launch_bounds__(256)
void logits_kernel(const void* __restrict__ x, const void* __restrict__ Wr,
                   const void* __restrict__ br, const int* __restrict__ kptr,
                   const int* __restrict__ flags, int* __restrict__ topk) {
  const bool xf32  = flags[0] != 0;
  const bool wrf32 = flags[1] != 0;
  const bool brf32 = flags[2] != 0;
  const int wave = threadIdx.x >> 6;
  const int lane = threadIdx.x & 63;
  const int t = blockIdx.x * 4 + wave;

  float xv[16];
  {
    size_t base = (size_t)t * EMB + lane * 16;
    if (xf32) {
      const float* g = (const float*)x + base;
#pragma unroll
      for (int j = 0; j < 16; ++j) xv[j] = g[j];
    } else {
      bf16x8 u = *(const bf16x8*)((const __bf16*)x + base);
      bf16x8 v = *(const bf16x8*)((const __bf16*)x + base + 8);
#pragma unroll
      for (int j = 0; j < 8; ++j) { xv[j] = (float)u[j]; xv[8 + j] = (float)v[j]; }
    }
  }
  float acc[NE];
#pragma unroll
  for (int e = 0; e < NE; ++e) acc[e] = 0.f;
  if (wrf32) {
#pragma unroll
    for (int j = 0; j < 16; ++j) {
      const float* wr = (const float*)Wr + (size_t)(lane * 16 + j) * NE;
#pragma unroll
      for (int e = 0; e < NE; ++e) acc[e] += xv[j] * wr[e];
    }
  } else {
#pragma unroll
    for (int j = 0; j < 16; ++j) {
      bf16x8 wr = *(const bf16x8*)((const __bf16*)Wr + (size_t)(lane * 16 + j) * NE);
#pragma unroll
      for (int e = 0; e < NE; ++e) acc[e] += xv[j] * (float)wr[e];
    }
  }
#pragma unroll
  for (int e = 0; e < NE; ++e) {
#pragma unroll
    for (int off = 32; off > 0; off >>= 1)
      acc[e] += __shfl_xor(acc[e], off, 64);
  }
  if (lane == 0) {
    int k = kptr[0];
    if (k < 1) k = 1; if (k > NE) k = NE;
    float lg[NE];
#pragma unroll
    for (int e = 0; e < NE; ++e) lg[e] = acc[e] + eload(br, e, brf32);
    for (int s = 0; s < k; ++s) {
      int bi = 0; float bv = lg[0];
#pragma unroll
      for (int e = 1; e < NE; ++e) { if (lg[e] > bv) { bv = lg[e]; bi = e; } }
      lg[bi] = -3.0e38f;
      topk[t * 8 + s] = bi;
    }
  }
}

// ---------------- binning: histogram -> scan -> place ----------------
__global__ __launch_bounds__(128)
void bin1_kernel(const int* __restrict__ topk, const int* __restrict__ kptr,
                 int* __restrict__ bhist) {
  __shared__ int lhist[NE];
  if (threadIdx.x < NE) lhist[threadIdx.x] = 0;
  __syncthreads();
  int k = kptr[0];
  if (k < 1) k = 1; if (k > NE) k = NE;
  const int t = blockIdx.x * BINTOK + threadIdx.x;
  for (int s = 0; s < k; ++s) atomicAdd(&lhist[topk[t * 8 + s] & 7], 1);
  __syncthreads();
  if (threadIdx.x < NE) bhist[blockIdx.x * NE + threadIdx.x] = lhist[threadIdx.x];
}

__global__ __launch_bounds__(256)
void scan_kernel(int* __restrict__ bhist, int* __restrict__ counts, int* __restrict__ offsets) {
  __shared__ int sh[NBINB * NE];
  __shared__ int scnt[NE];
  __shared__ int soff[NE + 1];
  const int tid = threadIdx.x;
  for (int i = tid; i < NBINB * NE; i += 256) sh[i] = bhist[i];
  __syncthreads();
  if (tid < NE) {
    int s = 0;
    for (int b = 0; b < NBINB; ++b) s += sh[b * NE + tid];
    scnt[tid] = s;
  }
  __syncthreads();
  if (tid == 0) {
    int s = 0;
    for (int e = 0; e < NE; ++e) { soff[e] = s; s += scnt[e]; }
    soff[NE] = s;
  }
  __syncthreads();
  if (tid < NE) {
    int run = soff[tid];
    for (int b = 0; b < NBINB; ++b) {
      int v = sh[b * NE + tid];
      sh[b * NE + tid] = run;
      run += v;
    }
  }
  __syncthreads();
  for (int i = tid; i < NBINB * NE; i += 256) bhist[i] = sh[i];
  if (tid < NE) counts[tid] = scnt[tid];
  if (tid < NE + 1) offsets[tid] = soff[tid];
}

__global__ __launch_bounds__(128)
void bin2_kernel(const int* __restrict__ bhist, const int* __restrict__ offsets,
                 const int* __restrict__ kptr,
                 int* __restrict__ tok_list, int* __restrict__ tokmap) {
  __shared__ int lbase[NE];
  __shared__ int lcnt[NE];
  if (threadIdx.x < NE) {
    lbase[threadIdx.x] = bhist[blockIdx.x * NE + threadIdx.x];
    lcnt[threadIdx.x] = 0;
  }
  __syncthreads();
  int k = kptr[0];
  if (k < 1) k = 1; if (k > NE) k = NE;
  const int t = blockIdx.x * BINTOK + threadIdx.x;
  for (int s = 0; s < k; ++s) {
    int e = tokmap[t * 8 + s] & 7;
    int pos = atomicAdd(&lcnt[e], 1);
    int grow = lbase[e] + pos;                   // compact global row
    tok_list[e * T_TOK + (grow - offsets[e])] = t;
    tokmap[t * 8 + s] = (e << 16) | grow;
  }
}

// ---------------- per-expert transpose: [K][N] -> [N][K] bf16 ----------------
__global__ __launch_bounds__(256)
void transpose_kernel(const void* __restrict__ in, __bf16* __restrict__ out, int K, int N,
                      const int* __restrict__ flags, int fidx) {
  const bool f32 = flags[fidx] != 0;
  __shared__ __bf16 tile[64][65];
  size_t eoff = (size_t)blockIdx.z * (size_t)K * (size_t)N;
  int n0 = blockIdx.x * 64;
  int k0 = blockIdx.y * 64;
  int tx = threadIdx.x & 63;
  int ty = threadIdx.x >> 6;
#pragma unroll
  for (int i = 0; i < 16; ++i) {
    int r = i * 4 + ty;
    tile[r][tx] = (__bf16)eload(in, eoff + (size_t)(k0 + r) * N + (n0 + tx), f32);
  }
  __syncthreads();
#pragma unroll
  for (int i = 0; i < 16; ++i) {
    int r = i * 4 + ty;
    out[eoff + (size_t)(n0 + r) * K + (k0 + tx)] = tile[tx][r];
  }
}

// ---------------- GEMM1: h = gelu(x_gather @ W1[e] + b1[e]) ----------------
// BK=32; bf16 fast path stages via global_load_lds width-16 (m97 pattern).
// Flat grid: e = flat&7 (XCD pin); within XCD: mT-groups of 8 x all nT.
__global__ __launch_bounds__(256, 2)
void gemm1_kernel(const void* __restrict__ x, const __bf16* __restrict__ w1t,
                  const void* __restrict__ b1, const int* __restrict__ counts,
                  const int* __restrict__ offsets, const int* __restrict__ tok_list,
                  const int* __restrict__ flags, __bf16* __restrict__ hbuf) {
  const int flat = blockIdx.x;
  const int e   = flat & 7;
  const int idx = flat >> 3;            // 0..767
  const int mTg = idx / 96;
  const int sub = idx % 96;
  const int nT  = sub >> 3;             // 0..11
  const int mT  = mTg * 8 + (sub & 7);  // 0..63
  const int cnt = counts[e];
  if (mT * 128 >= cnt) return;
  const bool xf32  = flags[0] != 0;
  const bool b1f32 = flags[4] != 0;

  __shared__ __align__(16) __bf16 As[128 * 32];
  __shared__ __align__(16) __bf16 Bs[128 * 32];

  const int wave = threadIdx.x >> 6;
  const int lane = threadIdx.x & 63;
  const int sr = lane >> 2;             // row within 16-row group
  const int kc = (lane & 3) * 8;        // k-chunk (16B)
  const int r0 = wave * 16 + sr;        // LDS row for chunk0
  const int r1 = 64 + wave * 16 + sr;   // LDS row for chunk1

  const int tokA0 = tok_list[e * T_TOK + mT * 128 + r0];  // pad entries = 0
  const int tokA1 = tok_list[e * T_TOK + mT * 128 + r1];
  const __bf16* xb = (const __bf16*)x;
  const __bf16* gA0 = xb + (size_t)tokA0 * EMB + kc;
  const __bf16* gA1 = xb + (size_t)tokA1 * EMB + kc;
  const __bf16* gB0 = w1t + ((size_t)e * HID + nT * 128 + r0) * EMB + kc;
  const __bf16* gB1 = w1t + ((size_t)e * HID + nT * 128 + r1) * EMB + kc;

  __bf16* lA0 = As + (wave * 16) * 32;        // wave-uniform bases; data lands at +lane*16B
  __bf16* lA1 = As + (64 + wave * 16) * 32;
  __bf16* lB0 = Bs + (wave * 16) * 32;
  __bf16* lB1 = Bs + (64 + wave * 16) * 32;

  const int wm = (wave & 1) * 64;
  const int wn = (wave >> 1) * 64;
  const int mr = lane & 15;
  const int kq8 = (lane >> 4) * 8;

  floatx4 acc[4][4];
#pragma unroll
  for (int i = 0; i < 4; ++i)
#pragma unroll
    for (int j = 0; j < 4; ++j) acc[i][j] = (floatx4){0.f, 0.f, 0.f, 0.f};

  if (!xf32) {
    for (int kb = 0; kb < EMB / 32; ++kb) {
      __syncthreads();                        // previous iteration's readers done
      glds16(gA0, lA0); glds16(gA1, lA1);
      glds16(gB0, lB0); glds16(gB1, lB1);
      gA0 += 32; gA1 += 32; gB0 += 32; gB1 += 32;
      __syncthreads();                        // vmcnt(0) drain -> LDS ready
      bf16x8 af[4], bfr[4];
#pragma unroll
      for (int i = 0; i < 4; ++i) af[i]  = *(const bf16x8*)(As + (wm + i * 16 + mr) * 32 + kq8);
#pragma unroll
      for (int j = 0; j < 4; ++j) bfr[j] = *(const bf16x8*)(Bs + (wn + j * 16 + mr) * 32 + kq8);
#pragma unroll
      for (int i = 0; i < 4; ++i)
#pragma unroll
        for (int j = 0; j < 4; ++j)
          acc[i][j] = __builtin_amdgcn_mfma_f32_16x16x32_bf16(af[i], bfr[j], acc[i][j], 0, 0, 0);
    }
  } else {
    // fp32-x fallback: register-staged (correctness path)
    size_t oA0 = (size_t)tokA0 * EMB + kc, oA1 = (size_t)tokA1 * EMB + kc;
    for (int kb = 0; kb < EMB / 32; ++kb) {
      bf16x8 a0 = ld8f32(x, oA0 + kb * 32);
      bf16x8 a1 = ld8f32(x, oA1 + kb * 32);
      bf16x8 b0 = *(const bf16x8*)(gB0 + kb * 32);
      bf16x8 b1v = *(const bf16x8*)(gB1 + kb * 32);
      __syncthreads();
      *(bf16x8*)(As + r0 * 32 + kc) = a0;
      *(bf16x8*)(As + r1 * 32 + kc) = a1;
      *(bf16x8*)(Bs + r0 * 32 + kc) = b0;
      *(bf16x8*)(Bs + r1 * 32 + kc) = b1v;
      __syncthreads();
      bf16x8 af[4], bfr[4];
#pragma unroll
      for (int i = 0; i < 4; ++i) af[i]  = *(const bf16x8*)(As + (wm + i * 16 + mr) * 32 + kq8);
#pragma unroll
      for (int j = 0; j < 4; ++j) bfr[j] = *(const bf16x8*)(Bs + (wn + j * 16 + mr) * 32 + kq8);
#pragma unroll
      for (int i = 0; i < 4; ++i)
#pragma unroll
        for (int j = 0; j < 4; ++j)
          acc[i][j] = __builtin_amdgcn_mfma_f32_16x16x32_bf16(af[i], bfr[j], acc[i][j], 0, 0, 0);
    }
  }

  const int hBase   = offsets[e] + mT * 128;
  const int colBase = nT * 128 + wn + mr;
  float b1v4[4];
#pragma unroll
  for (int j = 0; j < 4; ++j) b1v4[j] = eload(b1, (size_t)e * HID + colBase + j * 16, b1f32);
#pragma unroll
  for (int i = 0; i < 4; ++i) {
    const int rowLoc = wm + i * 16 + (lane >> 4) * 4;
#pragma unroll
    for (int r = 0; r < 4; ++r) {
      const int row = rowLoc + r;
      if (mT * 128 + row < cnt) {
        __bf16* hp = hbuf + (size_t)(hBase + row) * HID + colBase;
#pragma unroll
        for (int j = 0; j < 4; ++j) {
          float v = acc[i][j][r] + b1v4[j];
          float g = 0.5f * v * (1.0f + erff(v * 0.70710678118654752f));
          hp[j * 16] = (__bf16)g;
        }
      }
    }
  }
}

// ---------------- GEMM2: ybuf[row] = h @ W2[e] + b2[e]  (register-staged, r4-proven) ----------------
__global__ __launch_bounds__(256, 2)
void gemm2_kernel(const __bf16* __restrict__ hbuf, const __bf16* __restrict__ w2t,
                  const void* __restrict__ b2, const int* __restrict__ counts,
                  const int* __restrict__ offsets, const int* __restrict__ flags,
                  __bf16* __restrict__ ybuf) {
  const int flat = blockIdx.x;
  const int e   = flat & 7;
  const int idx = flat >> 3;            // 0..511
  const int mTg = idx >> 6;
  const int sub = idx & 63;
  const int nT  = sub >> 3;             // 0..7
  const int mT  = mTg * 8 + (sub & 7);  // 0..63
  const int cnt = counts[e];
  if (mT * 128 >= cnt) return;
  const bool b2f32 = flags[6] != 0;

  __shared__ __align__(16) __bf16 As[128 * 32];
  __shared__ __align__(16) __bf16 Bs[128 * 32];

  const int wave = threadIdx.x >> 6;
  const int lane = threadIdx.x & 63;
  const int sr = lane >> 2;
  const int kc = (lane & 3) * 8;
  const int r0 = wave * 16 + sr;
  const int r1 = 64 + wave * 16 + sr;

  const int rowBase = offsets[e] + mT * 128;
  const __bf16* gA0 = hbuf + (size_t)(rowBase + r0) * HID + kc;
  const __bf16* gA1 = hbuf + (size_t)(rowBase + r1) * HID + kc;
  const __bf16* gB0 = w2t + ((size_t)e * EMB + nT * 128 + r0) * HID + kc;
  const __bf16* gB1 = w2t + ((size_t)e * EMB + nT * 128 + r1) * HID + kc;

  const int wm = (wave & 1) * 64;
  const int wn = (wave >> 1) * 64;
  const int mr = lane & 15;
  const int kq8 = (lane >> 4) * 8;

  floatx4 acc[4][4];
#pragma unroll
  for (int i = 0; i < 4; ++i)
#pragma unroll
    for (int j = 0; j < 4; ++j) acc[i][j] = (floatx4){0.f, 0.f, 0.f, 0.f};

  bf16x8 s0 = *(const bf16x8*)gA0, s1 = *(const bf16x8*)gA1;
  bf16x8 s2 = *(const bf16x8*)gB0, s3 = *(const bf16x8*)gB1;
  const int niter = HID / 32;
  for (int kb = 0; kb < niter; ++kb) {
    bf16x8 n0 = s0, n1 = s1, n2 = s2, n3 = s3;
    if (kb + 1 < niter) {
      gA0 += 32; gA1 += 32; gB0 += 32; gB1 += 32;
      n0 = *(const bf16x8*)gA0; n1 = *(const bf16x8*)gA1;
      n2 = *(const bf16x8*)gB0; n3 = *(const bf16x8*)gB1;
    }
    __syncthreads();
    *(bf16x8*)(As + r0 * 32 + kc) = s0;
    *(bf16x8*)(As + r1 * 32 + kc) = s1;
    *(bf16x8*)(Bs + r0 * 32 + kc) = s2;
    *(bf16x8*)(Bs + r1 * 32 + kc) = s3;
    __syncthreads();
    bf16x8 af[4], bfr[4];
#pragma unroll
    for (int i = 0; i < 4; ++i) af[i]  = *(const bf16x8*)(As + (wm + i * 16 + mr) * 32 + kq8);
#pragma unroll
    for (int j = 0; j < 4; ++j) bfr[j] = *(const bf16x8*)(Bs + (wn + j * 16 + mr) * 32 + kq8);
#pragma unroll
    for (int i = 0; i < 4; ++i)
#pragma unroll
      for (int j = 0; j < 4; ++j)
        acc[i][j] = __builtin_amdgcn_mfma_f32_16x16x32_bf16(af[i], bfr[j], acc[i][j], 0, 0, 0);
    s0 = n0; s1 = n1; s2 = n2; s3 = n3;
  }

  const int colBase = nT * 128 + wn + mr;
  float b2v4[4];
#pragma unroll
  for (int j = 0; j < 4; ++j) b2v4[j] = eload(b2, (size_t)e * EMB + colBase + j * 16, b2f32);
#pragma unroll
  for (int i = 0; i < 4; ++i) {
    const int rowLoc = wm + i * 16 + (lane >> 4) * 4;
#pragma unroll
    for (int r = 0; r < 4; ++r) {
      const int row = rowLoc + r;
      if (mT * 128 + row < cnt) {
        __bf16* yp = ybuf + (size_t)(rowBase + row) * EMB + colBase;
#pragma unroll
        for (int j = 0; j < 4; ++j)
          yp[j * 16] = (__bf16)(acc[i][j][r] + b2v4[j]);
      }
    }
  }
}

// ---------------- combine: out[t] = (sum_s ybuf[row(t,s)]) / k ----------------
__global__ __launch_bounds__(256)
void combine_kernel(const __bf16* __restrict__ ybuf, const int* __restrict__ tokmap,
                    const int* __restrict__ kptr, const int* __restrict__ flags,
                    void* __restrict__ out) {
  const bool f32 = flags[0] != 0;
  const int wave = threadIdx.x >> 6;
  const int lane = threadIdx.x & 63;
  const int t = blockIdx.x * 4 + wave;
  int k = kptr[0];
  if (k < 1) k = 1; if (k > NE) k = NE;
  const float invk = 1.0f / (float)k;
  int rows[NE];
  for (int s = 0; s < k; ++s) rows[s] = tokmap[t * 8 + s] & 0xFFFF;
#pragma unroll
  for (int c = 0; c < 2; ++c) {
    const int i = c * 512 + lane * 8;
    float a[8];
#pragma unroll
    for (int j = 0; j < 8; ++j) a[j] = 0.f;
    for (int s = 0; s < k; ++s) {
      bf16x8 y = *(const bf16x8*)(ybuf + (size_t)rows[s] * EMB + i);
#pragma unroll
      for (int j = 0; j < 8; ++j) a[j] += (float)y[j];
    }
    if (f32) {
      float* op = (float*)out + (size_t)t * EMB + i;
      float4 u = {a[0] * invk, a[1] * invk, a[2] * invk, a[3] * invk};
      float4 v = {a[4] * invk, a[5] * invk, a[6] * invk, a[7] * invk};
      *(float4*)op = u;
      *(float4*)(op + 4) = v;
    } else {
      bf16x8 o;
#pragma unroll
      for (int j = 0; j < 8; ++j) o[j] = (__bf16)(a[j] * invk);
      *(bf16x8*)((__bf16*)out + (size_t)t * EMB + i) = o;
    }
  }
}

extern "C" void kernel_launch(void* const* d_in, const int* in_sizes, int n_in,
                              void* d_out, int out_size, void* d_ws, size_t ws_size,
                              hipStream_t stream) {
  (void)in_sizes; (void)n_in; (void)out_size;
  if (ws_size < (size_t)WS_NEEDED) return;

  const void* x  = d_in[0];
  const void* Wr = d_in[1];
  const void* br = d_in[2];
  const void* W1 = d_in[3];
  const void* b1 = d_in[4];
  const void* W2 = d_in[5];
  const void* b2 = d_in[6];
  const int* kptr = (const int*)d_in[7];

  char* ws = (char*)d_ws;
  int*    counts   = (int*)(ws + WS_COUNTS);
  int*    offsets  = (int*)(ws + WS_OFFSETS);
  int*    flags    = (int*)(ws + WS_FLAGS);
  int*    bhist    = (int*)(ws + WS_BHIST);
  int*    tokmap   = (int*)(ws + WS_TOKMAP);
  int*    tok_list = (int*)(ws + WS_TOKLIST);
  __bf16* ybuf     = (__bf16*)(ws + WS_YBUF);
  __bf16* w1t      = (__bf16*)(ws + WS_W1T);
  __bf16* w2t      = (__bf16*)(ws + WS_W2T);
  __bf16* hbuf     = (__bf16*)(ws + WS_H);

  hipMemsetAsync(ws, 0, WS_YBUF, stream);

  sniff_kernel<<<dim3(7), 256, 0, stream>>>(x, Wr, br, W1, b1, W2, b2, flags);

  transpose_kernel<<<dim3(HID / 64, EMB / 64, NE), 256, 0, stream>>>(W1, w1t, EMB, HID, flags, 3);
  transpose_kernel<<<dim3(EMB / 64, HID / 64, NE), 256, 0, stream>>>(W2, w2t, HID, EMB, flags, 5);

  logits_kernel<<<dim3(T_TOK / 4), 256, 0, stream>>>(x, Wr, br, kptr, flags, tokmap);
  bin1_kernel<<<dim3(NBINB), 128, 0, stream>>>(tokmap, kptr, bhist);
  scan_kernel<<<dim3(1), 256, 0, stream>>>(bhist, counts, offsets);
  bin2_kernel<<<dim3(NBINB), 128, 0, stream>>>(bhist, offsets, kptr, tok_list, tokmap);

  gemm1_kernel<<<dim3(8 * 64 * (HID / 128)), 256, 0, stream>>>(
      x, w1t, b1, counts, offsets, tok_list, flags, hbuf);
  gemm2_kernel<<<dim3(8 * 64 * (EMB / 128)), 256, 0, stream>>>(
      hbuf, w2t, b2, counts, offsets, flags, ybuf);

  combine_kernel<<<dim3(T_TOK / 4), 256, 0, stream>>>(ybuf, tokmap, kptr, flags, d_out);
}